// Round 13
// baseline (234.119 us; speedup 1.0000x reference)
//
#include <hip/hip_runtime.h>

// BEV pooling (Lift-Splat-Shoot) via CSR-style row buckets, MI355X / gfx950.
// MEASUREMENT ROUND 2: kernels byte-identical to R12. Graph = (init+fill)x3,
// gather x5 (idempotent). Combined with R8/R11 durations this solves the
// per-kernel split exactly:  dur = 154 + 2*G  =>  G=(dur-154)/2, I+F=48.6-G.

#define BNX 128
#define BNY 128
#define BNZ 16
#define BC  80
#define ACCP 81                    // padded acc stride (bank spread for store phase)
#define PLANE      (BNX * BNY)     // 16384
#define NSEG_PER_B (BNZ * PLANE)   // 262144
#define ZX         (BNZ * BNX)     // 2048 rows per batch
#define KCAP 1024                  // bucket capacity (row mean 27.5, sigma ~5)
#define GT 512                     // gather block size

typedef float fvec4 __attribute__((ext_vector_type(4)));

// ---- kernel 0: row_cnt = 0 -------------------------------------------------
__global__ __launch_bounds__(256) void init_cnt(int* __restrict__ cnt, int n)
{
    int i = blockIdx.x * blockDim.x + threadIdx.x;
    if (i < n) cnt[i] = 0;
}

// ---- kernel 1: fill row buckets -------------------------------------------
__global__ __launch_bounds__(256) void fill_buckets(
    const int* __restrict__ geom,
    int* __restrict__ row_cnt,   // [B*ZX]
    int* __restrict__ plist,     // [B*ZX*KCAP], entries (p<<7)|y
    int npoints, int per_b)
{
    int p = blockIdx.x * blockDim.x + threadIdx.x;
    if (p >= npoints) return;

    int gx = geom[p * 3 + 0];
    int gy = geom[p * 3 + 1];
    int gz = geom[p * 3 + 2];
    if ((unsigned)gx >= (unsigned)BNX ||
        (unsigned)gy >= (unsigned)BNY ||
        (unsigned)gz >= (unsigned)BNZ) return;

    int b   = p / per_b;
    int row = b * ZX + gz * BNX + gx;
    int pos = atomicAdd(&row_cnt[row], 1);
    if (pos < KCAP) plist[(size_t)row * KCAP + pos] = (p << 7) | gy;
}

// ---- kernel 2: row gather --------------------------------------------------
__global__ __launch_bounds__(GT) void gather_rows(
    const float* __restrict__ x,
    const int* __restrict__ plist,
    const int* __restrict__ row_cnt,
    float* __restrict__ out)
{
    __shared__ float acc[BNY * ACCP];   // 41.5 KB
    __shared__ int   list[KCAP];        // 4 KB

    const int tid = threadIdx.x;
    const int row = blockIdx.x;                 // b*ZX + zx
    const int b   = row / ZX;
    const int zx  = row - b * ZX;

    int n = row_cnt[row];
    n = n < KCAP ? n : KCAP;

    for (int i = tid; i < n; i += GT) list[i] = plist[(size_t)row * KCAP + i];
    for (int i = tid; i < BNY * ACCP; i += GT) acc[i] = 0.f;
    __syncthreads();

    if (tid < 500) {
        const int s  = tid / 20;      // entry slot 0..24
        const int cq = tid % 20;      // channel quad 0..19
        for (int i = s; i < n; i += 25) {
            int e  = list[i];
            int pp = e >> 7;
            int yy = e & 127;
            const fvec4 xv = *reinterpret_cast<const fvec4*>(
                &x[(size_t)pp * BC + cq * 4]);
            float* a = &acc[yy * ACCP + cq * 4];
            atomicAdd(&a[0], xv.x);
            atomicAdd(&a[1], xv.y);
            atomicAdd(&a[2], xv.z);
            atomicAdd(&a[3], xv.w);
        }
    }
    __syncthreads();

    {
        const int l  = tid & 31;          // y-quad: y = 4l..4l+3
        const int c0 = tid >> 5;          // 0..15
        size_t rowbase = (size_t)b * BC * NSEG_PER_B + (size_t)zx * BNY + 4 * l;
        for (int cc = c0; cc < BC; cc += 16) {
            fvec4 v;
            v.x = acc[(4 * l + 0) * ACCP + cc];
            v.y = acc[(4 * l + 1) * ACCP + cc];
            v.z = acc[(4 * l + 2) * ACCP + cc];
            v.w = acc[(4 * l + 3) * ACCP + cc];
            *reinterpret_cast<fvec4*>(&out[rowbase + (size_t)cc * NSEG_PER_B]) = v;
        }
    }
}

extern "C" void kernel_launch(void* const* d_in, const int* in_sizes, int n_in,
                              void* d_out, int out_size, void* d_ws, size_t ws_size,
                              hipStream_t stream)
{
    const float* x  = (const float*)d_in[0];
    const int* geom = (const int*)d_in[1];
    float* out      = (float*)d_out;

    const int npoints = in_sizes[0] / BC;                 // 473088
    const int B       = out_size / (BC * NSEG_PER_B);     // 1
    const int per_b   = npoints / (B > 0 ? B : 1);
    const int nrows   = B * ZX;                           // 2048

    int* row_cnt = (int*)d_ws;             // [nrows]
    int* plist   = row_cnt + nrows;        // [nrows*KCAP] = 8 MB

    // (init+fill) x3 — each fill preceded by fresh init => idempotent
    for (int rep = 0; rep < 3; ++rep) {
        init_cnt<<<(nrows + 255) / 256, 256, 0, stream>>>(row_cnt, nrows);
        fill_buckets<<<(npoints + 255) / 256, 256, 0, stream>>>(
            geom, row_cnt, plist, npoints, per_b);
    }
    // gather x5 — identical overwrites => idempotent
    for (int rep = 0; rep < 5; ++rep) {
        gather_rows<<<nrows, GT, 0, stream>>>(x, plist, row_cnt, out);
    }
}

// Round 14
// 33.476 us; speedup vs baseline: 6.9936x; 6.9936x over previous
//
#include <hip/hip_runtime.h>

// BEV pooling (Lift-Splat-Shoot) via CELL-level CSR, register accumulation.
// MI355X / gfx950.
//
//   x:    flat (Nprime=473088, C=80) f32
//   geom: flat (Nprime, 3) i32
//   out:  (B, C=80, NZ=16, NX=128, NY=128) f32
//
// R13 decomposition: gather = 40us of 48.6us pipeline; its LDS machinery
// (zero + atomicAdd storm + conflicted transpose + 3 barriers) is the only
// unfalsified suspect. This version: per-CELL CSR (cap 16 = one 64B line),
// gather has NO LDS / NO atomics / NO barriers — thread (cs,y) register-
// accumulates 20 channels of its cell and stores straight to global,
// 256B-coalesced per wave.

#define BNX 128
#define BNY 128
#define BNZ 16
#define BC  80
#define PLANE      (BNX * BNY)     // 16384
#define NSEG_PER_B (BNZ * PLANE)   // 262144
#define ZX         (BNZ * BNX)     // 2048 rows per batch
#define CCAP 16                    // per-cell capacity (mean 0.21, P(>=16)~1e-25)
#define GT 512                     // gather block size

typedef float fvec4 __attribute__((ext_vector_type(4)));

// ---- kernel 0: cellcnt = 0 (1MB per batch), int4-wide ----------------------
__global__ __launch_bounds__(256) void init_cnt(int4* __restrict__ cnt4, int n4)
{
    int i = blockIdx.x * blockDim.x + threadIdx.x;
    if (i < n4) cnt4[i] = make_int4(0, 0, 0, 0);
}

// ---- kernel 1: fill cell CSR ----------------------------------------------
__global__ __launch_bounds__(256) void fill_cells(
    const int* __restrict__ geom,
    int* __restrict__ cellcnt,    // [B*NSEG_PER_B]
    int* __restrict__ celllist,   // [B*NSEG_PER_B*CCAP]
    int npoints, int per_b)
{
    int p = blockIdx.x * blockDim.x + threadIdx.x;
    if (p >= npoints) return;

    int gx = geom[p * 3 + 0];
    int gy = geom[p * 3 + 1];
    int gz = geom[p * 3 + 2];
    if ((unsigned)gx >= (unsigned)BNX ||
        (unsigned)gy >= (unsigned)BNY ||
        (unsigned)gz >= (unsigned)BNZ) return;

    int b    = p / per_b;
    int cell = ((b * BNZ + gz) * BNX + gx) * BNY + gy;   // (b,z,x,y)
    int pos  = atomicAdd(&cellcnt[cell], 1);
    if (pos < CCAP) celllist[(size_t)cell * CCAP + pos] = p;
}

// ---- kernel 2: gather, pure registers --------------------------------------
// grid = B*ZX blocks (one per (b,z,x) row), 512 threads = 4 c-slots x 128 y.
// Wave = 64 consecutive y, fixed c-slot -> every global access coalesced.
__global__ __launch_bounds__(GT) void gather_csr(
    const float* __restrict__ x,
    const int* __restrict__ cellcnt,
    const int* __restrict__ celllist,
    float* __restrict__ out)
{
    const int tid = threadIdx.x;
    const int cs  = tid >> 7;          // channel slot 0..3 (20 channels each)
    const int y   = tid & 127;
    const int row = blockIdx.x;        // b*ZX + z*BNX + x
    const int b   = row >> 11;         // ZX = 2048
    const int zx  = row & (ZX - 1);

    const int cell = row * BNY + y;
    int m = cellcnt[cell];             // coalesced 256B per wave
    m = m < CCAP ? m : CCAP;

    fvec4 a0 = {0,0,0,0}, a1 = {0,0,0,0}, a2 = {0,0,0,0},
          a3 = {0,0,0,0}, a4 = {0,0,0,0};

    const int* cl = &celllist[(size_t)cell * CCAP];   // one 64B line
    for (int k = 0; k < m; ++k) {
        int p = cl[k];
        const fvec4* xr = reinterpret_cast<const fvec4*>(
            &x[(size_t)p * BC + cs * 20]);            // 80B contiguous
        a0 += xr[0]; a1 += xr[1]; a2 += xr[2]; a3 += xr[3]; a4 += xr[4];
    }

    // 20 scalar stores; per wave-instruction: 64 consecutive y, same channel
    // => 256B contiguous. Empty cells naturally write zeros.
    size_t obase = (size_t)(b * BC + cs * 20) * NSEG_PER_B
                 + (size_t)zx * BNY + y;
    float v[20] = { a0.x,a0.y,a0.z,a0.w, a1.x,a1.y,a1.z,a1.w,
                    a2.x,a2.y,a2.z,a2.w, a3.x,a3.y,a3.z,a3.w,
                    a4.x,a4.y,a4.z,a4.w };
    #pragma unroll
    for (int j = 0; j < 20; ++j)
        out[obase + (size_t)j * NSEG_PER_B] = v[j];
}

extern "C" void kernel_launch(void* const* d_in, const int* in_sizes, int n_in,
                              void* d_out, int out_size, void* d_ws, size_t ws_size,
                              hipStream_t stream)
{
    const float* x  = (const float*)d_in[0];
    const int* geom = (const int*)d_in[1];
    float* out      = (float*)d_out;

    const int npoints = in_sizes[0] / BC;                 // 473088
    const int B       = out_size / (BC * NSEG_PER_B);     // 1
    const int per_b   = npoints / (B > 0 ? B : 1);
    const int ncell   = B * NSEG_PER_B;                   // 262144*B

    int* cellcnt  = (int*)d_ws;                // [ncell]   (1MB/batch)
    int* celllist = cellcnt + ncell;           // [ncell*CCAP] (16MB/batch)

    const int n4 = ncell / 4;
    init_cnt<<<(n4 + 255) / 256, 256, 0, stream>>>((int4*)cellcnt, n4);

    fill_cells<<<(npoints + 255) / 256, 256, 0, stream>>>(
        geom, cellcnt, celllist, npoints, per_b);

    gather_csr<<<B * ZX, GT, 0, stream>>>(x, cellcnt, celllist, out);
}